// Round 6
// baseline (104.038 us; speedup 1.0000x reference)
//
#include <hip/hip_runtime.h>
#include <hip/hip_bf16.h>

#define B_N   8192
#define DIN   512
#define DH    512
#define NACT  18
#define NTASK 16
#define BM    64
#define GBN   128
#define BK    64
#define PJ    20      // pbuf row stride (floats)
#define NSLOT 640     // 8 residues x 80 queue slots

typedef __attribute__((ext_vector_type(8))) short  short8v;
typedef __attribute__((ext_vector_type(8))) unsigned short ushort8v;
typedef __attribute__((ext_vector_type(4))) float  float4v;
typedef __attribute__((ext_vector_type(2))) float  float2v;

__device__ __forceinline__ unsigned short bfbits(float f) {
  __hip_bfloat16 b = __float2bfloat16(f);   // RNE, compiler emits v_cvt_pk_bf16_f32
  return *reinterpret_cast<unsigned short*>(&b);
}

// ============================================================ prep: ONE block
// quartered histogram + 16-entry prefix + quartered scatter + zero tile_cnt
__global__ __launch_bounds__(1024) void k_prep(
    const int* __restrict__ task_id,
    int* __restrict__ tbl, int* __restrict__ rowidx, int* __restrict__ tile_cnt) {
  __shared__ int c4[4][NTASK];
  __shared__ int cur4[4][NTASK];
  int tid = threadIdx.x;
  if (tid < 64) ((int*)c4)[tid] = 0;
  for (int i = tid; i < NTASK * 128; i += 1024) tile_cnt[i] = 0;
  __syncthreads();
  for (int i = tid; i < B_N; i += 1024)
    atomicAdd(&c4[i >> 11][task_id[i]], 1);
  __syncthreads();
  if (tid == 0) {
    int acc = 0;
    for (int t = 0; t < NTASK; ++t) {
      int c = c4[0][t] + c4[1][t] + c4[2][t] + c4[3][t];
      tbl[t] = c; tbl[16 + t] = acc;
      int o = acc;
#pragma unroll
      for (int q = 0; q < 4; ++q) { cur4[q][t] = o; o += c4[q][t]; }
      acc += c;
    }
  }
  __syncthreads();
  for (int i = tid; i < B_N; i += 1024) {
    int t = task_id[i];
    rowidx[atomicAdd(&cur4[i >> 11][t], 1)] = i;
  }
}

// ============================================================ fused grouped GEMM
// Stages W1 (f32 native) with in-LDS transpose, W2 (f32 native) in-block.
// GEMM1 (64x128 tile) -> relu h in LDS -> partial GEMM2 -> pbuf; last block
// of the 4 col-slices reduces + softmax + writes out.
__global__ __launch_bounds__(256, 2) void k_gemm1(
    const float* __restrict__ x, const float* __restrict__ bias1,
    const float* __restrict__ W1, const float* __restrict__ W2,
    const float* __restrict__ bias2, const int* __restrict__ action,
    const int* __restrict__ tbl, const int* __restrict__ rowidx,
    int* __restrict__ tile_cnt, float* __restrict__ pbuf,
    float* __restrict__ out) {
  __shared__ __align__(16) short sA[2][BM * 72];    // 2 x 9 KB (padded)
  __shared__ __align__(16) short sB[2][GBN * BK];   // 2 x 16 KB (XOR-swz [n][k])
  __shared__ __align__(16) short sH[BM * GBN];      // 16 KB
  __shared__ __align__(16) short sW2[32 * GBN];     // 8 KB
  __shared__ int s_rows[64];
  __shared__ int s_last;
  int tid = threadIdx.x, lane = tid & 63, wave = tid >> 6;

  // ---- decode (uniform): residue b&7 == task&7 -> XCD affinity
  int b = blockIdx.x;
  int t = -1, rel = 0;
  if (b < NSLOT) {
    int r = b & 7, q = b >> 3;
    int n0t = (tbl[r] + 63) >> 6, n1t = (tbl[r + 8] + 63) >> 6;
    if (q < 4 * n0t) { t = r; rel = q; }
    else if (q < 4 * (n0t + n1t)) { t = r + 8; rel = q - 4 * n0t; }
    else return;
  } else {
    int j = b - NSLOT;
    for (int r = 0; r < 8; ++r) {
      int n0t = (tbl[r] + 63) >> 6, n1t = (tbl[r + 8] + 63) >> 6;
      int P = 4 * (n0t + n1t);
      int S = (P > 80) ? (P - 80) : 0;
      if (j < S) {
        int q = 80 + j;
        if (q < 4 * n0t) { t = r; rel = q; }
        else { t = r + 8; rel = q - 4 * n0t; }
        break;
      }
      j -= S;
    }
    if (t < 0) return;
  }
  int itile = rel >> 2, cs = rel & 3;
  int cnt_t = tbl[t], off_t = tbl[16 + t];
  int row0 = off_t + itile * 64;
  int mcnt = cnt_t - itile * 64; if (mcnt > 64) mcnt = 64;
  int n0 = cs * GBN;
  int wm = wave >> 1, wn = wave & 1;

  if (tid < 64) {
    int idx = row0 + tid;
    if (idx > B_N - 1) idx = B_N - 1;
    s_rows[tid] = rowidx[idx];
  }
  // ---- stage W2 slice from native [t][k][18] -> sW2 [j][k] chunk-swz bf16
#pragma unroll
  for (int it = 0; it < 2; ++it) {
    int slot = it * 256 + tid;           // 512 chunks: 32 j x 16 kc
    int j = slot & 31, kc = slot >> 5;
    int jc = (j < NACT) ? j : 0;
    const float* src = W2 + ((size_t)t * DIN + n0 + kc * 8) * NACT + jc;
    ushort8v pk;
#pragma unroll
    for (int i = 0; i < 8; ++i) {
      float v = src[(size_t)i * NACT];
      pk[i] = (j < NACT) ? bfbits(v) : (unsigned short)0;
    }
    *(ushort8v*)((char*)sW2 + (j * 16 + (kc ^ (j & 7))) * 16) = pk;
  }
  __syncthreads();

  // ---- staging setup
  int arow = tid >> 2, akc = (tid & 3) << 4;       // A: 4 thr/row, 16 k each
  const float* xrow = x + (size_t)s_rows[arow] * DIN + akc;
  int bk8 = tid >> 5, bn4 = tid & 31;              // B: k-oct x n-quad
  const float* w1base = W1 + (size_t)t * DIN * DH + n0 + bn4 * 4;

  float4v La[4], Lb[8];
#define LOAD_A(k0e) { _Pragma("unroll") for (int j_ = 0; j_ < 4; ++j_) \
    La[j_] = *(const float4v*)(xrow + (k0e) + j_ * 4); }
#define WRITE_A(buf) { ushort8v p0, p1;                                   \
    _Pragma("unroll") for (int i_ = 0; i_ < 4; ++i_) {                    \
      p0[i_] = bfbits(La[0][i_]); p0[4 + i_] = bfbits(La[1][i_]);         \
      p1[i_] = bfbits(La[2][i_]); p1[4 + i_] = bfbits(La[3][i_]); }       \
    *(ushort8v*)&sA[buf][arow * 72 + akc] = p0;                           \
    *(ushort8v*)&sA[buf][arow * 72 + akc + 8] = p1; }
#define LOAD_B(k0e) { _Pragma("unroll") for (int j_ = 0; j_ < 8; ++j_) \
    Lb[j_] = *(const float4v*)(w1base + (size_t)((k0e) + bk8 * 8 + j_) * DH); }
#define WRITE_B(buf) { _Pragma("unroll") for (int c_ = 0; c_ < 4; ++c_) { \
    int n_ = bn4 * 4 + c_;                                                \
    ushort8v pk;                                                          \
    _Pragma("unroll") for (int j_ = 0; j_ < 8; ++j_)                      \
      pk[j_] = bfbits(Lb[j_][c_]);                                        \
    *(ushort8v*)((char*)sB[buf] + n_ * 128 + ((bk8 ^ (n_ & 7)) << 4)) = pk; } }

  LOAD_A(0) LOAD_B(0)
  WRITE_A(0) WRITE_B(0)
  __syncthreads();

  float4v acc[2][4];
#pragma unroll
  for (int i = 0; i < 2; ++i)
#pragma unroll
    for (int j = 0; j < 4; ++j) acc[i][j] = (float4v)0.0f;

  for (int step = 0; step < 8; ++step) {
    int p = step & 1;
    if (step < 7) { LOAD_A((step + 1) * BK) LOAD_B((step + 1) * BK) }
#pragma unroll
    for (int ks = 0; ks < 2; ++ks) {
      short8v a[2], bfr[4];
#pragma unroll
      for (int fm = 0; fm < 2; ++fm) {
        int r = wm * 32 + fm * 16 + (lane & 15);
        int c = ks * 4 + (lane >> 4);
        a[fm] = *(const short8v*)&sA[p][r * 72 + c * 8];
      }
#pragma unroll
      for (int fn = 0; fn < 4; ++fn) {
        int r = wn * 64 + fn * 16 + (lane & 15);
        int c = (ks * 4 + (lane >> 4)) ^ (r & 7);
        bfr[fn] = *(const short8v*)&sB[p][r * BK + c * 8];
      }
#pragma unroll
      for (int fm = 0; fm < 2; ++fm)
#pragma unroll
        for (int fn = 0; fn < 4; ++fn)
          acc[fm][fn] = __builtin_amdgcn_mfma_f32_16x16x32_bf16(a[fm], bfr[fn], acc[fm][fn], 0, 0, 0);
    }
    if (step < 7) { WRITE_A(p ^ 1) WRITE_B(p ^ 1) }
    __syncthreads();
  }

  // ---- epilogue-1: +bias, relu, bf16 -> sH [m][n] chunk-swizzled
  float bias[4];
#pragma unroll
  for (int fn = 0; fn < 4; ++fn)
    bias[fn] = bias1[t * DH + n0 + wn * 64 + fn * 16 + (lane & 15)];
#pragma unroll
  for (int fn = 0; fn < 4; ++fn) {
    int n = wn * 64 + fn * 16 + (lane & 15);
#pragma unroll
    for (int fm = 0; fm < 2; ++fm) {
#pragma unroll
      for (int r = 0; r < 4; ++r) {
        int m = wm * 32 + fm * 16 + ((lane >> 4) << 2) + r;
        float v = fmaxf(acc[fm][fn][r] + bias[fn], 0.0f);
        *(short*)((char*)sH + m * 256 + (((n >> 3) ^ (m & 7)) << 4) + ((n & 7) << 1)) =
            (short)bfbits(v);
      }
    }
  }
  __syncthreads();

  // ---- partial GEMM2: this block's 128-n slice == 128-k slice of layer 2
  float4v acc2[2];
  acc2[0] = (float4v)0.0f; acc2[1] = (float4v)0.0f;
#pragma unroll
  for (int ks = 0; ks < 4; ++ks) {
    int mrow = wave * 16 + (lane & 15);
    int ca = (ks * 4 + (lane >> 4)) ^ (mrow & 7);
    short8v af = *(const short8v*)((char*)sH + mrow * 256 + (ca << 4));
#pragma unroll
    for (int fn = 0; fn < 2; ++fn) {
      int j = fn * 16 + (lane & 15);
      int cb = (ks * 4 + (lane >> 4)) ^ (j & 7);
      short8v bf = *(const short8v*)&sW2[(j * 16 + cb) * 8];
      acc2[fn] = __builtin_amdgcn_mfma_f32_16x16x32_bf16(af, bf, acc2[fn], 0, 0, 0);
    }
  }
#pragma unroll
  for (int fn = 0; fn < 2; ++fn) {
#pragma unroll
    for (int r = 0; r < 4; ++r) {
      int m = wave * 16 + ((lane >> 4) << 2) + r;
      int j = fn * 16 + (lane & 15);
      if (m < mcnt && j < PJ)
        pbuf[((size_t)cs * B_N + row0 + m) * PJ + j] = acc2[fn][r];
    }
  }

  // ---- completion counter: last of the 4 cs-blocks reduces + softmax
  __threadfence();                       // release partials (device scope)
  __syncthreads();                       // all waves' stores issued before count
  if (tid == 0) {
    int key = (t << 7) | itile;
    s_last = (atomicAdd(&tile_cnt[key], 1) == 3) ? 1 : 0;
  }
  __syncthreads();
  if (s_last) {
    __threadfence();                     // acquire
    if (tid < mcnt) {
      int m = tid, orig = s_rows[m];
      int act = action[orig];
      float lg[NACT];
#pragma unroll
      for (int j = 0; j < NACT; ++j) {
        float v = bias2[t * NACT + j];
#pragma unroll
        for (int c = 0; c < 4; ++c)
          v += pbuf[((size_t)c * B_N + row0 + m) * PJ + j];
        lg[j] = v;
      }
      float mx = lg[0];
#pragma unroll
      for (int j = 1; j < NACT; ++j) mx = fmaxf(mx, lg[j]);
      float s1 = 0.0f, s2 = 0.0f, la = 0.0f;
#pragma unroll
      for (int j = 0; j < NACT; ++j) {
        float e = __expf(lg[j] - mx);
        s1 += e; s2 += e * lg[j];
        la = (j == act) ? lg[j] : la;
      }
      float logZ = __logf(s1);
      float2v o;
      o[0] = la - mx - logZ;
      o[1] = (mx + logZ) - s2 / s1;
      *(float2v*)(out + (size_t)orig * 2) = o;
    }
  }
#undef LOAD_A
#undef WRITE_A
#undef LOAD_B
#undef WRITE_B
}

// ----------------------------------------------------------------------------
extern "C" void kernel_launch(void* const* d_in, const int* in_sizes, int n_in,
                              void* d_out, int out_size, void* d_ws, size_t ws_size,
                              hipStream_t stream) {
  const float* x       = (const float*)d_in[0];
  const int*   task_id = (const int*)d_in[1];
  const int*   action  = (const int*)d_in[2];
  const float* W1      = (const float*)d_in[3];
  const float* b1      = (const float*)d_in[4];
  const float* W2      = (const float*)d_in[5];
  const float* b2      = (const float*)d_in[6];
  float* out = (float*)d_out;

  char* ws = (char*)d_ws;
  int* tbl      = (int*)ws;                // 32 ints: [0:16) cnt, [16:32) offset
  int* rowidx   = (int*)(ws + 4096);       // 8192 ints -> ends 36864
  int* tile_cnt = (int*)(ws + 36864);      // 2048 ints -> ends 45056
  float* pbuf   = (float*)(ws + 45056);    // 4*8192*20 f32 = 2.62 MB

  k_prep<<<1, 1024, 0, stream>>>(task_id, tbl, rowidx, tile_cnt);
  k_gemm1<<<NSLOT + 576, 256, 0, stream>>>(x, b1, W1, W2, b2, action,
                                           tbl, rowidx, tile_cnt, pbuf, out);
}

// Round 7
// 72.254 us; speedup vs baseline: 1.4399x; 1.4399x over previous
//
#include <hip/hip_runtime.h>
#include <hip/hip_bf16.h>

#define B_N   8192
#define DIN   512
#define DH    512
#define NACT  18
#define NTASK 16
#define NQ    40
#define NSLOT 320     // NQ * 8 residues
#define SPILL 272     // max total 32-row tiles

typedef __attribute__((ext_vector_type(8))) short  short8v;
typedef __attribute__((ext_vector_type(8))) unsigned short ushort8v;
typedef __attribute__((ext_vector_type(4))) float  float4v;
typedef __attribute__((ext_vector_type(2))) float  float2v;

__device__ __forceinline__ unsigned short bfbits(float f) {
  union { float f; unsigned int u; } c; c.f = f;
  unsigned int u = c.u;
  u += 0x7fffu + ((u >> 16) & 1u);   // RNE
  return (unsigned short)(u >> 16);
}

// tbl layout: [0:16) cnt, [16:32) row offset, [32:48) padded row offset, [48] n padded 16-tiles

// ============================================================ hist (1 block)
__global__ __launch_bounds__(1024) void k_hist(
    const int* __restrict__ task_id, int* __restrict__ tbl, int* __restrict__ rowidx) {
  __shared__ int c4[4][NTASK], cur4[4][NTASK];
  int tid = threadIdx.x;
  if (tid < 64) ((int*)c4)[tid] = 0;
  __syncthreads();
  for (int i = tid; i < B_N; i += 1024) atomicAdd(&c4[i >> 11][task_id[i]], 1);
  __syncthreads();
  if (tid == 0) {
    int acc = 0, pacc = 0;
#pragma unroll
    for (int t = 0; t < NTASK; ++t) {
      int c = c4[0][t] + c4[1][t] + c4[2][t] + c4[3][t];
      tbl[t] = c; tbl[16 + t] = acc; tbl[32 + t] = pacc;
      int o = acc;
#pragma unroll
      for (int q = 0; q < 4; ++q) { cur4[q][t] = o; o += c4[q][t]; }
      acc += c;
      pacc += ((c + 31) >> 5) << 5;
    }
    tbl[48] = pacc >> 4;
  }
  __syncthreads();
  for (int i = tid; i < B_N; i += 1024) {
    int t = task_id[i];
    rowidx[atomicAdd(&cur4[i >> 11][t], 1)] = i;
  }
}

// ============================================================ pack kernel
// Fragment-major packing for mfma_f32_16x16x32_bf16:
//   frag chunk addr (16B units) = (frag_id*16 + kstep)*64 + lane,
//   lane = (outer&15) | (((k>>3)&3)<<4), byte = (k&7)*2.
// b < 1024      : W1 -> W1F   (residue-mapped so task t packs on XCD t&7)
// 1024<=b<1040  : W2 -> W2F
// b >= 1040     : x  -> xsF   (task-padded 16-row tiles, sorted rows)
__global__ __launch_bounds__(256) void k_pack(
    const float* __restrict__ x, const float* __restrict__ W1,
    const float* __restrict__ W2, const int* __restrict__ tbl,
    const int* __restrict__ rowidx,
    short* __restrict__ W1F, short* __restrict__ W2F, short* __restrict__ xsF) {
  __shared__ __align__(16) short ldsA[64][72];
  __shared__ float ldsB[64 * 19];
  int b = blockIdx.x, tid = threadIdx.x;

  if (b < 1024) {
    int r = b & 7, q = b >> 3;
    int t = r + 8 * (q >> 6);
    int sub = q & 63;
    int kb = sub >> 3, nb = sub & 7;
    // stage 64k x 64n tile, transposed to ldsA[n][k] bf16
    int kr = tid >> 2, c16 = (tid & 3) << 4;
    const float* src = W1 + ((size_t)t * DIN + (size_t)(kb * 64 + kr)) * DH + nb * 64 + c16;
#pragma unroll
    for (int p = 0; p < 4; ++p) {
      float4v v = *(const float4v*)(src + p * 4);
#pragma unroll
      for (int i = 0; i < 4; ++i) ldsA[c16 + p * 4 + i][kr] = (short)bfbits(v[i]);
    }
    __syncthreads();
    // emit fragment chunks: 512 chunks (4 nfrag x 2 kstep x 64 lane)
#pragma unroll
    for (int it = 0; it < 2; ++it) {
      int idx = it * 256 + tid;
      int nf = idx >> 7, ksl = (idx >> 6) & 1, lane = idx & 63;
      int n_l = nf * 16 + (lane & 15);
      int k_l = ksl * 32 + (lane >> 4) * 8;
      ushort8v v = *(ushort8v*)&ldsA[n_l][k_l];
      size_t fid = ((size_t)t * 32 + nb * 4 + nf) * 16 + kb * 2 + ksl;
      *(ushort8v*)(W1F + (fid * 64 + lane) * 8) = v;
    }
  } else if (b < 1040) {
    int t = b - 1024;
    for (int kb = 0; kb < 8; ++kb) {
      __syncthreads();
      for (int i = tid; i < 64 * NACT; i += 256) {
        int kk = i / NACT, j = i - kk * NACT;
        ldsB[kk * 19 + j] = W2[((size_t)t * DIN + kb * 64 + kk) * NACT + j];
      }
      __syncthreads();
      // 256 chunks: 2 kstep x 2 jfrag x 64 lane
      int ksl = tid >> 7, jf = (tid >> 6) & 1, lane = tid & 63;
      int j = jf * 16 + (lane & 15);
      int k_l = ksl * 32 + (lane >> 4) * 8;
      ushort8v pk;
#pragma unroll
      for (int i = 0; i < 8; ++i) {
        float v = (j < NACT) ? ldsB[(k_l + i) * 19 + j] : 0.0f;
        pk[i] = (j < NACT) ? bfbits(v) : (unsigned short)0;
      }
      size_t fid = ((size_t)t * 2 + jf) * 16 + kb * 2 + ksl;
      *(ushort8v*)(W2F + (fid * 64 + lane) * 8) = pk;
    }
  } else {
    int pt = b - 1040;
    if (pt >= tbl[48]) return;
    // find task containing padded tile pt
    int t = 0;
#pragma unroll
    for (int s = 0; s < NTASK; ++s) {
      int pof = tbl[32 + s];
      int pcnt = ((tbl[s] + 31) >> 5) << 5;
      if (pt * 16 >= pof && pt * 16 < pof + pcnt) t = s;
    }
    int L0 = pt * 16 - tbl[32 + t];
    int cnt = tbl[t], off = tbl[16 + t];
#pragma unroll
    for (int it = 0; it < 4; ++it) {
      int idx = it * 256 + tid;
      int kstep = idx >> 6, lane = idx & 63;
      int L = L0 + (lane & 15);
      int srow = off + ((L < cnt) ? L : (cnt - 1));
      int orig = rowidx[srow];
      const float* px = x + (size_t)orig * DIN + kstep * 32 + (lane >> 4) * 8;
      float4v v0 = *(const float4v*)px;
      float4v v1 = *(const float4v*)(px + 4);
      ushort8v pk;
#pragma unroll
      for (int i = 0; i < 4; ++i) { pk[i] = bfbits(v0[i]); pk[4 + i] = bfbits(v1[i]); }
      *(ushort8v*)(xsF + (((size_t)pt * 16 + kstep) * 64 + lane) * 8) = pk;
    }
  }
}

// ============================================================ fused GEMM1+GEMM2+softmax
// 32-row tiles, 4 waves: wave = (mfrag = w&1, n-half = w>>1). No LDS / no barriers
// in the K-loop: operands stream from fragment-major L2-resident buffers.
__global__ __launch_bounds__(256, 2) void k_fused(
    const short* __restrict__ xsF, const short* __restrict__ W1F,
    const short* __restrict__ W2F, const float* __restrict__ bias1,
    const float* __restrict__ bias2, const int* __restrict__ task_id,
    const int* __restrict__ action, const int* __restrict__ tbl,
    const int* __restrict__ rowidx, float* __restrict__ out) {
  __shared__ __align__(16) short sH[32 * 512];   // 32 KB, chunk-XOR swizzled
  __shared__ float slog[32 * 36];                // 4.6 KB
  __shared__ int s_rows[32];
  int tid = threadIdx.x, lane = tid & 63, wave = tid >> 6;

  // ---- decode: residue r serves tasks {r, r+8}
  int b = blockIdx.x;
  int t = -1, tile = 0;
  if (b < NSLOT) {
    int r = b & 7, q = b >> 3;
    int T0 = (tbl[r] + 31) >> 5, T1 = (tbl[r + 8] + 31) >> 5;
    if (q < T0) { t = r; tile = q; }
    else if (q < T0 + T1) { t = r + 8; tile = q - T0; }
    else return;
  } else {
    int j = b - NSLOT;
    for (int r = 0; r < 8; ++r) {
      int T0 = (tbl[r] + 31) >> 5, T1 = (tbl[r + 8] + 31) >> 5;
      int S = (T0 + T1 > NQ) ? (T0 + T1 - NQ) : 0;
      if (j < S) {
        int q = NQ + j;
        if (q < T0) { t = r; tile = q; }
        else { t = r + 8; tile = q - T0; }
        break;
      }
      j -= S;
    }
    if (t < 0) return;
  }
  int cnt = tbl[t], off = tbl[16 + t];
  int row0 = off + tile * 32;
  int mcnt = cnt - tile * 32; if (mcnt > 32) mcnt = 32;
  int pt0 = (tbl[32 + t] >> 4) + tile * 2;

  if (tid < 32) s_rows[tid] = rowidx[row0 + ((tid < mcnt) ? tid : (mcnt - 1))];
  __syncthreads();

  int mf = wave & 1, nh = wave >> 1;

  // ---- GEMM1: free-running fragment streams
  const short8v* Af = (const short8v*)xsF + ((size_t)(pt0 + mf) * 16) * 64 + lane;
  const short8v* Bf = (const short8v*)W1F + (((size_t)t * 32 + nh * 16) * 16) * 64 + lane;
  float4v acc[16];
#pragma unroll
  for (int i = 0; i < 16; ++i) acc[i] = (float4v)0.0f;
#pragma unroll
  for (int ks = 0; ks < 16; ++ks) {
    short8v a = Af[(size_t)ks * 64];
#pragma unroll
    for (int nf = 0; nf < 16; ++nf) {
      short8v bb = Bf[((size_t)nf * 16 + ks) * 64];
      acc[nf] = __builtin_amdgcn_mfma_f32_16x16x32_bf16(a, bb, acc[nf], 0, 0, 0);
    }
  }

  // ---- h -> sH (bias + relu + bf16), chunk-XOR swizzled rows of 1 KB
#pragma unroll
  for (int nf = 0; nf < 16; ++nf) {
    int n = nh * 256 + nf * 16 + (lane & 15);
    float bias = bias1[t * DH + n];
#pragma unroll
    for (int r = 0; r < 4; ++r) {
      int m = mf * 16 + ((lane >> 4) << 2) + r;
      float v = fmaxf(acc[nf][r] + bias, 0.0f);
      *(short*)((char*)sH + m * 1024 + (((n >> 3) ^ (m & 7)) << 4) + ((n & 7) << 1)) =
          (short)bfbits(v);
    }
  }
  __syncthreads();

  // ---- GEMM2: wave = (mfrag = w&1, jfrag = w>>1)
  int jf = wave >> 1;
  const short8v* Wf = (const short8v*)W2F + (((size_t)t * 2 + jf) * 16) * 64 + lane;
  float4v acc2 = (float4v)0.0f;
#pragma unroll
  for (int ks = 0; ks < 16; ++ks) {
    int row = mf * 16 + (lane & 15);
    int c = ks * 4 + (lane >> 4);
    short8v ah = *(const short8v*)((char*)sH + row * 1024 + ((c ^ (row & 7)) << 4));
    short8v bw = Wf[(size_t)ks * 64];
    acc2 = __builtin_amdgcn_mfma_f32_16x16x32_bf16(ah, bw, acc2, 0, 0, 0);
  }
#pragma unroll
  for (int r = 0; r < 4; ++r) {
    int m = mf * 16 + ((lane >> 4) << 2) + r;
    int j = jf * 16 + (lane & 15);
    slog[m * 36 + j] = acc2[r];
  }
  __syncthreads();

  // ---- softmax + entropy (threads 0..31, one row each)
  if (tid < 32 && tid < mcnt) {
    int orig = s_rows[tid];
    int act = action[orig];
    float lg[NACT];
#pragma unroll
    for (int j = 0; j < NACT; ++j) lg[j] = slog[tid * 36 + j] + bias2[t * NACT + j];
    float mx = lg[0];
#pragma unroll
    for (int j = 1; j < NACT; ++j) mx = fmaxf(mx, lg[j]);
    float s1 = 0.0f, s2 = 0.0f, la = 0.0f;
#pragma unroll
    for (int j = 0; j < NACT; ++j) {
      float e = __expf(lg[j] - mx);
      s1 += e; s2 += e * lg[j];
      la = (j == act) ? lg[j] : la;
    }
    float logZ = __logf(s1);
    float2v o;
    o[0] = la - mx - logZ;
    o[1] = (mx + logZ) - s2 / s1;
    *(float2v*)(out + (size_t)orig * 2) = o;
  }
}

// ----------------------------------------------------------------------------
extern "C" void kernel_launch(void* const* d_in, const int* in_sizes, int n_in,
                              void* d_out, int out_size, void* d_ws, size_t ws_size,
                              hipStream_t stream) {
  const float* x       = (const float*)d_in[0];
  const int*   task_id = (const int*)d_in[1];
  const int*   action  = (const int*)d_in[2];
  const float* W1      = (const float*)d_in[3];
  const float* b1      = (const float*)d_in[4];
  const float* W2      = (const float*)d_in[5];
  const float* b2      = (const float*)d_in[6];
  float* out = (float*)d_out;

  char* ws = (char*)d_ws;
  int* tbl    = (int*)ws;                  // 64 ints
  int* rowidx = (int*)(ws + 4096);         // 8192 ints -> ends 36864
  size_t off = 36864;
  short* W1F = (short*)(ws + off);  off += (size_t)16 * 32 * 16 * 64 * 16;  // 8.39 MB
  short* W2F = (short*)(ws + off);  off += (size_t)16 * 2 * 16 * 64 * 16;   // 0.52 MB
  short* xsF = (short*)(ws + off);  off += (size_t)544 * 16 * 64 * 16;      // 8.91 MB

  k_hist<<<1, 1024, 0, stream>>>(task_id, tbl, rowidx);
  k_pack<<<1040 + 544, 256, 0, stream>>>(x, W1, W2, tbl, rowidx, W1F, W2F, xsF);
  k_fused<<<NSLOT + SPILL, 256, 0, stream>>>(xsF, W1F, W2F, b1, b2, task_id,
                                             action, tbl, rowidx, out);
}